// Round 7
// baseline (728.648 us; speedup 1.0000x reference)
//
#include <hip/hip_runtime.h>
#include <hip/hip_cooperative_groups.h>
#include <cmath>

namespace cg = cooperative_groups;

#define N_MET   100000
#define N_RXN   200000
#define E_SUB   400000
#define E_PROD  400000
#define HIDDEN  128
#define MSG_DIM 64
#define DT      0.01f
#define TGRID   32
#define TGP     33
#define NPTS    (TGP * TGP)
#define NCELL   (TGRID * TGRID)
#define NB1     ((N_RXN + 255) / 256)          // 782
#define CHUNK   16
#define NCHUNKS ((N_RXN + CHUNK - 1) / CHUNK)  // 12500

__device__ __forceinline__ float fast_tanh(float x) {
    float t = __expf(2.0f * x);
    return 1.0f - 2.0f * __builtin_amdgcn_rcpf(t + 1.0f);
}

__device__ __forceinline__ float softplus_f(float x) {
    return (x > 20.0f) ? x : log1pf(__expf(x));
}

__device__ __forceinline__ float bcastf(float v, int l) {
    return __int_as_float(__builtin_amdgcn_readlane(__float_as_int(v), l));
}

// M[j][d] = sum_m W2[j][m] * V1[m][d]  (128x128), row 128 = b2 @ V1 bias
__global__ void mm_kernel(const float* __restrict__ W2, const float* __restrict__ V1,
                          const float* __restrict__ b2, float* __restrict__ M) {
    int j = blockIdx.x;      // 0..128
    int d = threadIdx.x;     // 0..127
    float acc = 0.0f;
    if (j < HIDDEN) {
        for (int m = 0; m < MSG_DIM; ++m)
            acc = fmaf(W2[j * MSG_DIM + m], V1[m * HIDDEN + d], acc);
        M[j * HIDDEN + d] = acc;
    } else {
        for (int m = 0; m < MSG_DIM; ++m)
            acc = fmaf(b2[m], V1[m * HIDDEN + d], acc);
        M[HIDDEN * HIDDEN + d] = acc;
    }
}

// One block per grid point; writes its 128-dim g into up to 4 quad-cells.
// Cell layout (2 KB): lane l holds 2 float4:
//   q0 = {c00[l], c00[l+64], c01[l], c01[l+64]}
//   q1 = {c10[l], c10[l+64], c11[l], c11[l+64]}
__global__ void __launch_bounds__(128)
gtable_kernel(const float* __restrict__ W1, const float* __restrict__ b1,
              const float* __restrict__ M, float* __restrict__ tq) {
    __shared__ float h_s[HIDDEN];
    int d = threadIdx.x;
    int p = blockIdx.x;
    int ia = p / TGP, ib = p % TGP;
    float a = (float)ia * (1.0f / TGRID);
    float b = 0.5f + (float)ib * (1.0f / TGRID);
    h_s[d] = tanhf(fmaf(a, W1[d], fmaf(b, W1[HIDDEN + d], b1[d])));
    __syncthreads();
    float acc = M[HIDDEN * HIDDEN + d];     // bias row (b2 @ V1)
    #pragma unroll 4
    for (int j = 0; j < HIDDEN; ++j)
        acc = fmaf(h_s[j], M[j * HIDDEN + d], acc);
    int l = d & 63, hi = d >> 6;
    int lofs = l * 8 + hi;
    if (ia < TGRID && ib < TGRID) tq[(ia * TGRID + ib) * 512 + lofs + 0] = acc;           // c00
    if (ia < TGRID && ib > 0)     tq[(ia * TGRID + ib - 1) * 512 + lofs + 2] = acc;       // c01
    if (ia > 0 && ib < TGRID)     tq[((ia - 1) * TGRID + ib) * 512 + lofs + 4] = acc;     // c10
    if (ia > 0 && ib > 0)         tq[((ia - 1) * TGRID + ib - 1) * 512 + lofs + 6] = acc; // c11
}

// Cooperative: zero-cnt + histogram + 3-level scan + finalize/zero + scatter
// in ONE dispatch (replaces 5 kernels + 1 memset). Grid must be exactly NB1.
__global__ void __launch_bounds__(256)
build_csr(const int* __restrict__ rxn_sub,
          int* __restrict__ cnt, int* __restrict__ off, int* __restrict__ woff,
          int* __restrict__ bsum, int* __restrict__ pay,
          float* __restrict__ tot, float* __restrict__ out) {
    cg::grid_group grid = cg::this_grid();
    __shared__ int wsum[4];
    __shared__ int carry_s;
    int tid = blockIdx.x * blockDim.x + threadIdx.x;
    int nth = gridDim.x * blockDim.x;
    int lane = threadIdx.x & 63, w = threadIdx.x >> 6;
    // P0: zero cnt
    for (int i = tid; i < N_RXN; i += nth) cnt[i] = 0;
    grid.sync();
    // P1: histogram
    for (int i = tid; i < E_SUB; i += nth) atomicAdd(&cnt[rxn_sub[i]], 1);
    grid.sync();
    // P2: per-block exclusive scan (grid == NB1, block b owns [b*256, b*256+256))
    {
        int i = blockIdx.x * 256 + threadIdx.x;
        int v = (i < N_RXN) ? cnt[i] : 0;
        int s = v;
        #pragma unroll
        for (int d2 = 1; d2 < 64; d2 <<= 1) {
            int u = __shfl_up(s, d2);
            if (lane >= d2) s += u;
        }
        if (lane == 63) wsum[w] = s;
        __syncthreads();
        int pre = 0;
        #pragma unroll
        for (int q = 0; q < 4; ++q) if (q < w) pre += wsum[q];
        if (i < N_RXN) off[i] = pre + s - v;
        if (threadIdx.x == 255) bsum[blockIdx.x] = pre + s;
        __syncthreads();
    }
    grid.sync();
    // P3: scan of block sums (block 0 only, 256 threads, 4 serial chunks)
    if (blockIdx.x == 0) {
        if (threadIdx.x == 0) carry_s = 0;
        __syncthreads();
        for (int c0 = 0; c0 < NB1; c0 += 256) {
            int i = c0 + threadIdx.x;
            int v = (i < NB1) ? bsum[i] : 0;
            int s = v;
            #pragma unroll
            for (int d2 = 1; d2 < 64; d2 <<= 1) {
                int u = __shfl_up(s, d2);
                if (lane >= d2) s += u;
            }
            if (lane == 63) wsum[w] = s;
            __syncthreads();
            int pre = 0;
            #pragma unroll
            for (int q = 0; q < 4; ++q) if (q < w) pre += wsum[q];
            int total = wsum[0] + wsum[1] + wsum[2] + wsum[3];
            int carry = carry_s;
            if (i < NB1) bsum[i] = carry + pre + s - v;
            __syncthreads();
            if (threadIdx.x == 0) carry_s = carry + total;
            __syncthreads();
        }
    }
    grid.sync();
    // P4: finalize offsets; zero tot and out
    for (int i = tid; i < N_RXN; i += nth) {
        int wv = off[i] + bsum[i >> 8];
        off[i] = wv;
        woff[i] = wv;
    }
    for (int i = tid; i < N_MET; i += nth) { tot[i] = 0.0f; out[i] = 0.0f; }
    if (tid == 0) off[N_RXN] = E_SUB;
    grid.sync();
    // P5: scatter edge ids into rxn-CSR
    for (int i = tid; i < E_SUB; i += nth) {
        int p = atomicAdd(&woff[rxn_sub[i]], 1);
        pay[p] = i;
    }
}

// Wave = 16 consecutive reactions (static chunks, 12500 waves). Per 64-edge
// batch lanes precompute cell idx + blended weights; inner loop processes
// edges in groups of 4 with all 8 quad-cell dwordx4 loads hoisted -> 4x
// memory concurrency on the latency-bound gather stream.
__global__ void __launch_bounds__(256)
rxn_fused6(const float* __restrict__ x, const int* __restrict__ met_sub,
           const int* __restrict__ rxn_sub, const float* __restrict__ sto_sub,
           const int* __restrict__ off, const int* __restrict__ pay,
           const float4* __restrict__ tq,
           const float* __restrict__ c1, const float* __restrict__ V2,
           const float* __restrict__ c2, const float* __restrict__ log_k,
           float* __restrict__ v_out, float* __restrict__ tot) {
    __shared__ float vbuf[4][CHUNK];
    int lane = threadIdx.x & 63;
    int wslot = threadIdx.x >> 6;
    int wave = (blockIdx.x * blockDim.x + threadIdx.x) >> 6;
    int nwaves = (gridDim.x * blockDim.x) >> 6;
    float c1a = c1[lane], c1b = c1[64 + lane];
    float v2a = V2[lane], v2b = V2[64 + lane];
    float c2v = c2[0];
    for (int chunk = wave; chunk * CHUNK < N_RXN; chunk += nwaves) {
        int r0 = chunk * CHUNK;
        int offs = (lane <= CHUNK) ? off[r0 + lane] : 0;
        int start = __shfl(offs, 0);
        int end   = __shfl(offs, CHUNK);
        int cur = 0;
        int cur_start = start;
        int cur_end = __shfl(offs, 1);
        float za = c1a, zb = c1b, eacc = 0.0f;
        for (int p0 = start; p0 < end; p0 += 64) {
            int nchunk = end - p0; if (nchunk > 64) nchunk = 64;
            float w00 = 0.0f, w01 = 0.0f, w10 = 0.0f, w11 = 0.0f, xeb = 0.0f;
            int idx = 0;
            if (lane < nchunk) {
                int eid = pay[p0 + lane];
                float se = sto_sub[eid];
                int me = met_sub[eid];
                float ae = x[me * 8 + 3];
                xeb = x[me * 8 + 4];
                float fa = ae * (float)TGRID;
                float fb = (se - 0.5f) * (float)TGRID;
                int ia = (int)fa; ia = ia < 0 ? 0 : (ia > TGRID - 1 ? TGRID - 1 : ia);
                int ib = (int)fb; ib = ib < 0 ? 0 : (ib > TGRID - 1 ? TGRID - 1 : ib);
                float wa = fa - (float)ia, wb = fb - (float)ib;
                float ua = 1.0f - wa, ub = 1.0f - wb;
                w00 = ua * ub; w01 = ua * wb; w10 = wa * ub; w11 = wa * wb;
                idx = ia * TGRID + ib;
            }
            for (int jg = 0; jg < nchunk; jg += 4) {
                int ng = nchunk - jg; if (ng > 4) ng = 4;
                float4 q[8];
                float s00[4], s01[4], s10[4], s11[4], sxe[4];
                #pragma unroll
                for (int u = 0; u < 4; ++u) {
                    if (u < ng) {
                        int si = __builtin_amdgcn_readlane(idx, jg + u);
                        const float4* tp = tq + (size_t)si * 128 + lane * 2;
                        q[2 * u]     = tp[0];
                        q[2 * u + 1] = tp[1];
                        s00[u] = bcastf(w00, jg + u);
                        s01[u] = bcastf(w01, jg + u);
                        s10[u] = bcastf(w10, jg + u);
                        s11[u] = bcastf(w11, jg + u);
                        sxe[u] = bcastf(xeb, jg + u);
                    }
                }
                #pragma unroll
                for (int u = 0; u < 4; ++u) {
                    if (u >= ng) break;
                    int pe = p0 + jg + u;
                    while (pe >= cur_end) {              // wave-uniform finalize
                        float pp = fast_tanh(za) * v2a + fast_tanh(zb) * v2b;
                        #pragma unroll
                        for (int o = 32; o > 0; o >>= 1) pp += __shfl_xor(pp, o);
                        int r = r0 + cur;
                        int n = cur_end - cur_start;
                        float em = eacc / (float)(n > 0 ? n : 1);
                        if (lane == 0) {
                            float bv = softplus_f(pp + c2v);
                            float k  = __expf(log_k[r] * 2.302585092994046f);
                            float vr = k * em * bv;
                            v_out[r] = vr;
                            vbuf[wslot][cur] = vr;
                        }
                        cur++;
                        cur_start = cur_end;
                        cur_end = __shfl(offs, cur + 1);
                        za = c1a; zb = c1b; eacc = 0.0f;
                    }
                    za = fmaf(s00[u], q[2 * u].x, za); zb = fmaf(s00[u], q[2 * u].y, zb);
                    za = fmaf(s01[u], q[2 * u].z, za); zb = fmaf(s01[u], q[2 * u].w, zb);
                    za = fmaf(s10[u], q[2 * u + 1].x, za); zb = fmaf(s10[u], q[2 * u + 1].y, zb);
                    za = fmaf(s11[u], q[2 * u + 1].z, za); zb = fmaf(s11[u], q[2 * u + 1].w, zb);
                    eacc += sxe[u];
                }
            }
        }
        while (cur < CHUNK) {                        // tail finalize
            float pp = fast_tanh(za) * v2a + fast_tanh(zb) * v2b;
            #pragma unroll
            for (int o = 32; o > 0; o >>= 1) pp += __shfl_xor(pp, o);
            int r = r0 + cur;
            int n = cur_end - cur_start;
            float em = eacc / (float)(n > 0 ? n : 1);
            if (lane == 0) {
                float bv = softplus_f(pp + c2v);
                float k  = __expf(log_k[r] * 2.302585092994046f);
                float vr = k * em * bv;
                v_out[r] = vr;
                vbuf[wslot][cur] = vr;
            }
            cur++;
            if (cur < CHUNK) {
                cur_start = cur_end;
                cur_end = __shfl(offs, cur + 1);
                za = c1a; zb = c1b; eacc = 0.0f;
            }
        }
        // cons sweep: tot[met] += sto * v * DT  (v from LDS, loads warm in L2)
        for (int p0 = start; p0 < end; p0 += 64) {
            int nchunk = end - p0; if (nchunk > 64) nchunk = 64;
            if (lane < nchunk) {
                int eid = pay[p0 + lane];
                int r   = rxn_sub[eid];
                float vv = vbuf[wslot][r - r0];
                atomicAdd(&tot[met_sub[eid]], sto_sub[eid] * vv * DT);
            }
        }
    }
}

// Fused: reaction-parallel scale gather + v scale + substrate scatter.
__global__ void scale_out_kernel(const int* __restrict__ off, const int* __restrict__ pay,
                                 const int* __restrict__ met_sub, const float* __restrict__ sto_sub,
                                 const float* __restrict__ x, const float* __restrict__ tot,
                                 float* __restrict__ v, float* __restrict__ out) {
    int r = blockIdx.x * blockDim.x + threadIdx.x;
    if (r >= N_RXN) return;
    int s = off[r], e = off[r + 1];
    float sc = 1.0f;
    for (int p = s; p < e; ++p) {
        int m = met_sub[pay[p]];
        float tc = tot[m];
        if (tc > 1e-12f) sc = fminf(sc, fminf(x[m * 8 + 3] / tc, 1.0f));
    }
    float vr = v[r] * sc;
    v[r] = vr;
    for (int p = s; p < e; ++p) {
        int eid = pay[p];
        atomicAdd(&out[met_sub[eid]], -sto_sub[eid] * vr);
    }
}

__global__ void prod_out_kernel(const int* __restrict__ met_prod, const int* __restrict__ rxn_prod,
                                const float* __restrict__ sto_prod,
                                const float* __restrict__ v, float* __restrict__ out) {
    int e = blockIdx.x * blockDim.x + threadIdx.x;
    if (e < E_PROD)
        atomicAdd(&out[met_prod[e]], sto_prod[e] * v[rxn_prod[e]]);
}

extern "C" void kernel_launch(void* const* d_in, const int* in_sizes, int n_in,
                              void* d_out, int out_size, void* d_ws, size_t ws_size,
                              hipStream_t stream) {
    const float* x        = (const float*)d_in[0];
    const int*   met_sub  = (const int*)d_in[1];
    const int*   rxn_sub  = (const int*)d_in[2];
    const float* sto_sub  = (const float*)d_in[3];
    const int*   met_prod = (const int*)d_in[4];
    const int*   rxn_prod = (const int*)d_in[5];
    const float* sto_prod = (const float*)d_in[6];
    const float* W1       = (const float*)d_in[7];
    const float* b1       = (const float*)d_in[8];
    const float* W2       = (const float*)d_in[9];
    const float* b2       = (const float*)d_in[10];
    const float* V1       = (const float*)d_in[11];
    const float* c1       = (const float*)d_in[12];
    const float* V2       = (const float*)d_in[13];
    const float* c2       = (const float*)d_in[14];
    const float* log_k    = (const float*)d_in[15];

    int*   cnt  = (int*)d_ws;                        // N_RXN
    float* tot  = (float*)(cnt + N_RXN);             // N_MET
    int*   off  = (int*)(tot + N_MET);               // N_RXN + 1
    int*   woff = off + N_RXN + 1;                   // N_RXN
    int*   bsum = woff + N_RXN;                      // 1024
    int*   pay  = bsum + 1024;                       // E_SUB
    float* v    = (float*)(pay + E_SUB);             // N_RXN
    float* M    = v + N_RXN;                         // 128*128 + 128
    float* tq   = M + HIDDEN * HIDDEN + HIDDEN;      // NCELL*512 (2 MB)
    float* outf = (float*)d_out;

    mm_kernel<<<HIDDEN + 1, HIDDEN, 0, stream>>>(W2, V1, b2, M);
    gtable_kernel<<<NPTS, HIDDEN, 0, stream>>>(W1, b1, M, tq);

    void* args[] = {(void*)&rxn_sub, (void*)&cnt, (void*)&off, (void*)&woff,
                    (void*)&bsum, (void*)&pay, (void*)&tot, (void*)&outf};
    hipLaunchCooperativeKernel((const void*)build_csr, dim3(NB1), dim3(256),
                               args, 0, stream);

    rxn_fused6<<<3125, 256, 0, stream>>>(x, met_sub, rxn_sub, sto_sub, off, pay,
                                         (const float4*)tq, c1, V2, c2, log_k, v, tot);
    scale_out_kernel<<<NB1, 256, 0, stream>>>(off, pay, met_sub, sto_sub, x, tot, v, outf);
    prod_out_kernel<<<(E_PROD + 255) / 256, 256, 0, stream>>>(met_prod, rxn_prod, sto_prod, v, outf);
}

// Round 8
// 319.859 us; speedup vs baseline: 2.2780x; 2.2780x over previous
//
#include <hip/hip_runtime.h>
#include <cmath>

#define N_MET   100000
#define N_RXN   200000
#define E_SUB   400000
#define E_PROD  400000
#define HIDDEN  128
#define MSG_DIM 64
#define DT      0.01f
#define TGRID   32
#define TGP     33
#define NPTS    (TGP * TGP)
#define NCELL   (TGRID * TGRID)
#define NB1     ((N_RXN + 255) / 256)          // 782
#define CHUNK   16

__device__ __forceinline__ float fast_tanh(float x) {
    float t = __expf(2.0f * x);
    return 1.0f - 2.0f * __builtin_amdgcn_rcpf(t + 1.0f);
}

__device__ __forceinline__ float softplus_f(float x) {
    return (x > 20.0f) ? x : log1pf(__expf(x));
}

__device__ __forceinline__ float bcastf(float v, int l) {
    return __int_as_float(__builtin_amdgcn_readlane(__float_as_int(v), l));
}

// M[j][d] = sum_m W2[j][m] * V1[m][d]  (128x128), row 128 = b2 @ V1 bias
__global__ void mm_kernel(const float* __restrict__ W2, const float* __restrict__ V1,
                          const float* __restrict__ b2, float* __restrict__ M) {
    int j = blockIdx.x;      // 0..128
    int d = threadIdx.x;     // 0..127
    float acc = 0.0f;
    if (j < HIDDEN) {
        for (int m = 0; m < MSG_DIM; ++m)
            acc = fmaf(W2[j * MSG_DIM + m], V1[m * HIDDEN + d], acc);
        M[j * HIDDEN + d] = acc;
    } else {
        for (int m = 0; m < MSG_DIM; ++m)
            acc = fmaf(b2[m], V1[m * HIDDEN + d], acc);
        M[HIDDEN * HIDDEN + d] = acc;
    }
}

// One block per grid point; writes its 128-dim g into up to 4 quad-cells.
// Cell layout (2 KB): lane l holds 2 float4:
//   q0 = {c00[l], c00[l+64], c01[l], c01[l+64]}
//   q1 = {c10[l], c10[l+64], c11[l], c11[l+64]}
__global__ void __launch_bounds__(128)
gtable_kernel(const float* __restrict__ W1, const float* __restrict__ b1,
              const float* __restrict__ M, float* __restrict__ tq) {
    __shared__ float h_s[HIDDEN];
    int d = threadIdx.x;
    int p = blockIdx.x;
    int ia = p / TGP, ib = p % TGP;
    float a = (float)ia * (1.0f / TGRID);
    float b = 0.5f + (float)ib * (1.0f / TGRID);
    h_s[d] = tanhf(fmaf(a, W1[d], fmaf(b, W1[HIDDEN + d], b1[d])));
    __syncthreads();
    float acc = M[HIDDEN * HIDDEN + d];     // bias row (b2 @ V1)
    #pragma unroll 4
    for (int j = 0; j < HIDDEN; ++j)
        acc = fmaf(h_s[j], M[j * HIDDEN + d], acc);
    int l = d & 63, hi = d >> 6;
    int lofs = l * 8 + hi;
    if (ia < TGRID && ib < TGRID) tq[(ia * TGRID + ib) * 512 + lofs + 0] = acc;           // c00
    if (ia < TGRID && ib > 0)     tq[(ia * TGRID + ib - 1) * 512 + lofs + 2] = acc;       // c01
    if (ia > 0 && ib < TGRID)     tq[((ia - 1) * TGRID + ib) * 512 + lofs + 4] = acc;     // c10
    if (ia > 0 && ib > 0)         tq[((ia - 1) * TGRID + ib - 1) * 512 + lofs + 6] = acc; // c11
}

__global__ void hist_kernel(const int* __restrict__ rxn_sub, int* __restrict__ cnt) {
    int t = blockIdx.x * blockDim.x + threadIdx.x;
    if (t < E_SUB) atomicAdd(&cnt[rxn_sub[t]], 1);
}

__global__ void scan_l1(const int* __restrict__ cnt, int* __restrict__ off,
                        int* __restrict__ bsum) {
    __shared__ int wsum[4];
    int t = threadIdx.x, lane = t & 63, w = t >> 6;
    int i = blockIdx.x * 256 + t;
    int v = (i < N_RXN) ? cnt[i] : 0;
    int s = v;
    #pragma unroll
    for (int d = 1; d < 64; d <<= 1) {
        int u = __shfl_up(s, d);
        if (lane >= d) s += u;
    }
    if (lane == 63) wsum[w] = s;
    __syncthreads();
    int pre = 0;
    #pragma unroll
    for (int q = 0; q < 4; ++q) if (q < w) pre += wsum[q];
    if (i < N_RXN) off[i] = pre + s - v;
    if (t == 255) bsum[blockIdx.x] = pre + s;
}

__global__ void scan_l2(int* __restrict__ bsum) {
    __shared__ int wsum[16];
    int t = threadIdx.x, lane = t & 63, w = t >> 6;
    int v = (t < NB1) ? bsum[t] : 0;
    int s = v;
    #pragma unroll
    for (int d = 1; d < 64; d <<= 1) {
        int u = __shfl_up(s, d);
        if (lane >= d) s += u;
    }
    if (lane == 63) wsum[w] = s;
    __syncthreads();
    int pre = 0;
    #pragma unroll
    for (int q = 0; q < 16; ++q) if (q < w) pre += wsum[q];
    if (t < NB1) bsum[t] = pre + s - v;    // exclusive
}

__global__ void scan_l3(int* __restrict__ off, const int* __restrict__ bsum,
                        int* __restrict__ woff, float* __restrict__ tot,
                        float* __restrict__ out) {
    int i = blockIdx.x * blockDim.x + threadIdx.x;
    if (i < N_RXN) {
        int wv = off[i] + bsum[i >> 8];
        off[i] = wv;
        woff[i] = wv;
    }
    if (i < N_MET) { tot[i] = 0.0f; out[i] = 0.0f; }
    if (i == 0) off[N_RXN] = E_SUB;
}

__global__ void scatter_kernel(const int* __restrict__ rxn_sub,
                               int* __restrict__ woff, int* __restrict__ pay) {
    int t = blockIdx.x * blockDim.x + threadIdx.x;
    if (t < E_SUB) {
        int p = atomicAdd(&woff[rxn_sub[t]], 1);
        pay[p] = t;
    }
}

// Wave = 16 consecutive reactions (static chunks, 12500 waves). Per 64-edge
// batch lanes precompute cell idx + blended weights; inner loop processes
// edges in groups of 4 with all 8 quad-cell dwordx4 loads hoisted -> 4x
// memory concurrency on the latency-bound gather stream.
__global__ void __launch_bounds__(256)
rxn_fused6(const float* __restrict__ x, const int* __restrict__ met_sub,
           const int* __restrict__ rxn_sub, const float* __restrict__ sto_sub,
           const int* __restrict__ off, const int* __restrict__ pay,
           const float4* __restrict__ tq,
           const float* __restrict__ c1, const float* __restrict__ V2,
           const float* __restrict__ c2, const float* __restrict__ log_k,
           float* __restrict__ v_out, float* __restrict__ tot) {
    __shared__ float vbuf[4][CHUNK];
    int lane = threadIdx.x & 63;
    int wslot = threadIdx.x >> 6;
    int wave = (blockIdx.x * blockDim.x + threadIdx.x) >> 6;
    int nwaves = (gridDim.x * blockDim.x) >> 6;
    float c1a = c1[lane], c1b = c1[64 + lane];
    float v2a = V2[lane], v2b = V2[64 + lane];
    float c2v = c2[0];
    for (int chunk = wave; chunk * CHUNK < N_RXN; chunk += nwaves) {
        int r0 = chunk * CHUNK;
        int offs = (lane <= CHUNK) ? off[r0 + lane] : 0;
        int start = __shfl(offs, 0);
        int end   = __shfl(offs, CHUNK);
        int cur = 0;
        int cur_start = start;
        int cur_end = __shfl(offs, 1);
        float za = c1a, zb = c1b, eacc = 0.0f;
        for (int p0 = start; p0 < end; p0 += 64) {
            int nchunk = end - p0; if (nchunk > 64) nchunk = 64;
            float w00 = 0.0f, w01 = 0.0f, w10 = 0.0f, w11 = 0.0f, xeb = 0.0f;
            int idx = 0;
            if (lane < nchunk) {
                int eid = pay[p0 + lane];
                float se = sto_sub[eid];
                int me = met_sub[eid];
                float ae = x[me * 8 + 3];
                xeb = x[me * 8 + 4];
                float fa = ae * (float)TGRID;
                float fb = (se - 0.5f) * (float)TGRID;
                int ia = (int)fa; ia = ia < 0 ? 0 : (ia > TGRID - 1 ? TGRID - 1 : ia);
                int ib = (int)fb; ib = ib < 0 ? 0 : (ib > TGRID - 1 ? TGRID - 1 : ib);
                float wa = fa - (float)ia, wb = fb - (float)ib;
                float ua = 1.0f - wa, ub = 1.0f - wb;
                w00 = ua * ub; w01 = ua * wb; w10 = wa * ub; w11 = wa * wb;
                idx = ia * TGRID + ib;
            }
            for (int jg = 0; jg < nchunk; jg += 4) {
                int ng = nchunk - jg; if (ng > 4) ng = 4;
                float4 q[8];
                float s00[4], s01[4], s10[4], s11[4], sxe[4];
                #pragma unroll
                for (int u = 0; u < 4; ++u) {
                    if (u < ng) {
                        int si = __builtin_amdgcn_readlane(idx, jg + u);
                        const float4* tp = tq + (size_t)si * 128 + lane * 2;
                        q[2 * u]     = tp[0];
                        q[2 * u + 1] = tp[1];
                        s00[u] = bcastf(w00, jg + u);
                        s01[u] = bcastf(w01, jg + u);
                        s10[u] = bcastf(w10, jg + u);
                        s11[u] = bcastf(w11, jg + u);
                        sxe[u] = bcastf(xeb, jg + u);
                    }
                }
                #pragma unroll
                for (int u = 0; u < 4; ++u) {
                    if (u >= ng) break;
                    int pe = p0 + jg + u;
                    while (pe >= cur_end) {              // wave-uniform finalize
                        float pp = fast_tanh(za) * v2a + fast_tanh(zb) * v2b;
                        #pragma unroll
                        for (int o = 32; o > 0; o >>= 1) pp += __shfl_xor(pp, o);
                        int r = r0 + cur;
                        int n = cur_end - cur_start;
                        float em = eacc / (float)(n > 0 ? n : 1);
                        if (lane == 0) {
                            float bv = softplus_f(pp + c2v);
                            float k  = __expf(log_k[r] * 2.302585092994046f);
                            float vr = k * em * bv;
                            v_out[r] = vr;
                            vbuf[wslot][cur] = vr;
                        }
                        cur++;
                        cur_start = cur_end;
                        cur_end = __shfl(offs, cur + 1);
                        za = c1a; zb = c1b; eacc = 0.0f;
                    }
                    za = fmaf(s00[u], q[2 * u].x, za); zb = fmaf(s00[u], q[2 * u].y, zb);
                    za = fmaf(s01[u], q[2 * u].z, za); zb = fmaf(s01[u], q[2 * u].w, zb);
                    za = fmaf(s10[u], q[2 * u + 1].x, za); zb = fmaf(s10[u], q[2 * u + 1].y, zb);
                    za = fmaf(s11[u], q[2 * u + 1].z, za); zb = fmaf(s11[u], q[2 * u + 1].w, zb);
                    eacc += sxe[u];
                }
            }
        }
        while (cur < CHUNK) {                        // tail finalize
            float pp = fast_tanh(za) * v2a + fast_tanh(zb) * v2b;
            #pragma unroll
            for (int o = 32; o > 0; o >>= 1) pp += __shfl_xor(pp, o);
            int r = r0 + cur;
            int n = cur_end - cur_start;
            float em = eacc / (float)(n > 0 ? n : 1);
            if (lane == 0) {
                float bv = softplus_f(pp + c2v);
                float k  = __expf(log_k[r] * 2.302585092994046f);
                float vr = k * em * bv;
                v_out[r] = vr;
                vbuf[wslot][cur] = vr;
            }
            cur++;
            if (cur < CHUNK) {
                cur_start = cur_end;
                cur_end = __shfl(offs, cur + 1);
                za = c1a; zb = c1b; eacc = 0.0f;
            }
        }
        // cons sweep: tot[met] += sto * v * DT  (v from LDS, loads warm in L2)
        for (int p0 = start; p0 < end; p0 += 64) {
            int nchunk = end - p0; if (nchunk > 64) nchunk = 64;
            if (lane < nchunk) {
                int eid = pay[p0 + lane];
                int r   = rxn_sub[eid];
                float vv = vbuf[wslot][r - r0];
                atomicAdd(&tot[met_sub[eid]], sto_sub[eid] * vv * DT);
            }
        }
    }
}

// Fused: reaction-parallel scale gather + v scale + substrate scatter.
__global__ void scale_out_kernel(const int* __restrict__ off, const int* __restrict__ pay,
                                 const int* __restrict__ met_sub, const float* __restrict__ sto_sub,
                                 const float* __restrict__ x, const float* __restrict__ tot,
                                 float* __restrict__ v, float* __restrict__ out) {
    int r = blockIdx.x * blockDim.x + threadIdx.x;
    if (r >= N_RXN) return;
    int s = off[r], e = off[r + 1];
    float sc = 1.0f;
    for (int p = s; p < e; ++p) {
        int m = met_sub[pay[p]];
        float tc = tot[m];
        if (tc > 1e-12f) sc = fminf(sc, fminf(x[m * 8 + 3] / tc, 1.0f));
    }
    float vr = v[r] * sc;
    v[r] = vr;
    for (int p = s; p < e; ++p) {
        int eid = pay[p];
        atomicAdd(&out[met_sub[eid]], -sto_sub[eid] * vr);
    }
}

__global__ void prod_out_kernel(const int* __restrict__ met_prod, const int* __restrict__ rxn_prod,
                                const float* __restrict__ sto_prod,
                                const float* __restrict__ v, float* __restrict__ out) {
    int e = blockIdx.x * blockDim.x + threadIdx.x;
    if (e < E_PROD)
        atomicAdd(&out[met_prod[e]], sto_prod[e] * v[rxn_prod[e]]);
}

extern "C" void kernel_launch(void* const* d_in, const int* in_sizes, int n_in,
                              void* d_out, int out_size, void* d_ws, size_t ws_size,
                              hipStream_t stream) {
    const float* x        = (const float*)d_in[0];
    const int*   met_sub  = (const int*)d_in[1];
    const int*   rxn_sub  = (const int*)d_in[2];
    const float* sto_sub  = (const float*)d_in[3];
    const int*   met_prod = (const int*)d_in[4];
    const int*   rxn_prod = (const int*)d_in[5];
    const float* sto_prod = (const float*)d_in[6];
    const float* W1       = (const float*)d_in[7];
    const float* b1       = (const float*)d_in[8];
    const float* W2       = (const float*)d_in[9];
    const float* b2       = (const float*)d_in[10];
    const float* V1       = (const float*)d_in[11];
    const float* c1       = (const float*)d_in[12];
    const float* V2       = (const float*)d_in[13];
    const float* c2       = (const float*)d_in[14];
    const float* log_k    = (const float*)d_in[15];

    int*   cnt  = (int*)d_ws;                        // N_RXN
    float* tot  = (float*)(cnt + N_RXN);             // N_MET
    int*   off  = (int*)(tot + N_MET);               // N_RXN + 1
    int*   woff = off + N_RXN + 1;                   // N_RXN
    int*   bsum = woff + N_RXN;                      // 1024
    int*   pay  = bsum + 1024;                       // E_SUB
    float* v    = (float*)(pay + E_SUB);             // N_RXN
    float* M    = v + N_RXN;                         // 128*128 + 128
    float* tq   = M + HIDDEN * HIDDEN + HIDDEN;      // NCELL*512 (2 MB)
    float* outf = (float*)d_out;

    hipMemsetAsync(cnt, 0, (size_t)N_RXN * sizeof(int), stream);

    mm_kernel<<<HIDDEN + 1, HIDDEN, 0, stream>>>(W2, V1, b2, M);
    gtable_kernel<<<NPTS, HIDDEN, 0, stream>>>(W1, b1, M, tq);
    hist_kernel<<<(E_SUB + 255) / 256, 256, 0, stream>>>(rxn_sub, cnt);
    scan_l1<<<NB1, 256, 0, stream>>>(cnt, off, bsum);
    scan_l2<<<1, 1024, 0, stream>>>(bsum);
    scan_l3<<<NB1, 256, 0, stream>>>(off, bsum, woff, tot, outf);
    scatter_kernel<<<(E_SUB + 255) / 256, 256, 0, stream>>>(rxn_sub, woff, pay);
    rxn_fused6<<<3125, 256, 0, stream>>>(x, met_sub, rxn_sub, sto_sub, off, pay,
                                         (const float4*)tq, c1, V2, c2, log_k, v, tot);
    scale_out_kernel<<<NB1, 256, 0, stream>>>(off, pay, met_sub, sto_sub, x, tot, v, outf);
    prod_out_kernel<<<(E_PROD + 255) / 256, 256, 0, stream>>>(met_prod, rxn_prod, sto_prod, v, outf);
}